// Round 2
// baseline (6577.274 us; speedup 1.0000x reference)
//
#include <hip/hip_runtime.h>
#include <math.h>

#define HH 64
#define WW 64
#define NB 8
#define CIN 32
#define COUT 32
#define NT 50
#define HW (HH*WW)
#define CSX ((size_t)NT*HW)   // X channel stride
#define PITCH 20              // LDS pitch per pixel (16 ch + 4 pad)
#define TSZ (324*PITCH)       // one staging buffer (18x18 halo tile, 16 ch)

__device__ __forceinline__ float fsigmoid(float x) {
    return 1.0f / (1.0f + __expf(-x));
}
__device__ __forceinline__ float ftanh(float x) {
    float e = __expf(-2.0f * fabsf(x));
    float t = (1.0f - e) / (1.0f + e);
    return copysignf(t, x);
}

// Weight layouts (built once):
//  Wxt[((k*32+ci)*8+cg)*16 + g*4+o]
//  Wyt[((k*32+ci)*8+cg)*12 + g*4+o]
//  Wzt[((k*32+ci)*8+cg)*4  + o]
__global__ __launch_bounds__(256) void wtrans(
    const float* __restrict__ Wx, const float* __restrict__ Wy, const float* __restrict__ Wz,
    float* __restrict__ Wxt, float* __restrict__ Wyt, float* __restrict__ Wzt)
{
    int i = blockIdx.x * 256 + threadIdx.x;
    if (i < 36864) {
        int g = (i >> 2) & 3, o = i & 3;
        int q = i >> 4;
        int cg = q & 7, t2 = q >> 3;
        int ci = t2 & 31, k = t2 >> 5;
        int oc = g*32 + cg*4 + o;
        Wxt[i] = Wx[((size_t)oc*32 + ci)*9 + k];
    }
    if (i < 27648) {
        int r12 = i % 12, q = i / 12;
        int g = r12 >> 2, o = r12 & 3;
        int cg = q & 7, t2 = q >> 3;
        int ci = t2 & 31, k = t2 >> 5;
        int oc = g*32 + cg*4 + o;
        Wyt[i] = Wy[((size_t)oc*32 + ci)*9 + k];
    }
    if (i < 9216) {
        int o = i & 3, q = i >> 2;
        int cg = q & 7, t2 = q >> 3;
        int ci = t2 & 31, k = t2 >> 5;
        int oc = cg*4 + o;
        Wzt[i] = Wz[((size_t)oc*32 + ci)*9 + k];
    }
}

// ---- async staging: issue global loads early, ds_write late (T14 split) ----
// 16 channels of an 18x18 halo tile -> LDS [pix][16ch] pitch 20.
// Each thread handles up to 3 float4 units; channel stride is cstride.
struct StageRegs {
    float4 v[3];
    int    dst[3];   // LDS float offset, -1 if inactive
    int    inb[3];
};

__device__ __forceinline__ void stage_issue(StageRegs& s,
    const float* __restrict__ src, size_t cstride, int h0, int w0, int tid)
{
    #pragma unroll
    for (int it = 0; it < 3; ++it) {
        int idx = it*512 + tid;          // 1296 float4 units
        s.dst[it] = -1;
        if (idx < 1296) {
            int ci4 = idx / 324;
            int pix = idx - ci4*324;
            int rr = pix / 18, cc = pix - rr*18;
            int gh = h0 + rr - 1, gw = w0 + cc - 1;
            s.inb[it] = (int)((unsigned)gh < 64u) & (int)((unsigned)gw < 64u);
            int ghc = min(max(gh, 0), HH-1), gwc = min(max(gw, 0), WW-1);
            const float* p = src + (size_t)(ci4*4)*cstride + (ghc*WW + gwc);
            s.v[it].x = p[0];
            s.v[it].y = p[cstride];
            s.v[it].z = p[2*cstride];
            s.v[it].w = p[3*cstride];
            s.dst[it] = pix*PITCH + ci4*4;
        }
    }
}

__device__ __forceinline__ void stage_write(float* __restrict__ buf, const StageRegs& s)
{
    #pragma unroll
    for (int it = 0; it < 3; ++it) {
        if (s.dst[it] >= 0) {
            float4 q;
            q.x = s.inb[it] ? s.v[it].x : 0.0f;
            q.y = s.inb[it] ? s.v[it].y : 0.0f;
            q.z = s.inb[it] ? s.v[it].z : 0.0f;
            q.w = s.inb[it] ? s.v[it].w : 0.0f;
            *(float4*)&buf[s.dst[it]] = q;
        }
    }
}

// conv over one staged 16-channel chunk, NG gate groups of 4 outputs.
// wbase pre-offset for (chunk, cg); per-(k,ci) weight row is contiguous (scalar loads).
template<int NG>
__device__ __forceinline__ void conv_chunk(const float* __restrict__ buf,
    const float* __restrict__ wbase, int ty, int tx, float* __restrict__ acc)
{
    for (int k = 0; k < 9; ++k) {
        int kh = k/3, kw = k - kh*3;
        const float* lp = &buf[((ty+kh)*18 + tx+kw)*PITCH];
        const float* wp = wbase + (size_t)k*(32*8*NG*4);
        #pragma unroll
        for (int ci4 = 0; ci4 < 4; ++ci4) {
            float4 xv = *(const float4*)(lp + ci4*4);
            #pragma unroll
            for (int j = 0; j < 4; ++j) {
                float v = (j==0)?xv.x:(j==1)?xv.y:(j==2)?xv.z:xv.w;
                const float4* wr = (const float4*)(wp + (size_t)(ci4*4+j)*(8*NG*4));
                #pragma unroll
                for (int g = 0; g < NG; ++g) {
                    float4 wg = wr[g];
                    acc[g*4+0] = fmaf(v, wg.x, acc[g*4+0]);
                    acc[g*4+1] = fmaf(v, wg.y, acc[g*4+1]);
                    acc[g*4+2] = fmaf(v, wg.z, acc[g*4+2]);
                    acc[g*4+3] = fmaf(v, wg.w, acc[g*4+3]);
                }
            }
        }
    }
}

// Kernel A: xconv (4 gates) + yconv (3 gates) + Z update; writes Z, ms2, xy.
// 512 threads = two 256-thread halves computing two channel-groups off ONE staged tile.
// Double-buffered LDS: stage chunk c+1 overlaps compute of chunk c.
__global__ __launch_bounds__(512, 4) void lem_gates(
    const float* __restrict__ X,
    const float* __restrict__ Wxt, const float* __restrict__ bx,
    const float* __restrict__ Wyt, const float* __restrict__ by,
    const float* __restrict__ Y, float* __restrict__ Z,
    float* __restrict__ ms2w, float* __restrict__ xyw, int t)
{
    __shared__ __align__(16) float tile[2][TSZ];   // 51,840 B
    const int tid = threadIdx.x;
    const int tx = tid & 15, ty = (tid >> 4) & 15;
    const int half = __builtin_amdgcn_readfirstlane(tid >> 8);
    const int w0 = blockIdx.x * 16, h0 = blockIdx.y * 16;
    const int b  = blockIdx.z >> 2;
    const int cg = ((blockIdx.z & 3) << 1) | half;

    const float* xb = X + ((size_t)b*CIN*NT + t)*HW;
    const float* yb = Y + (size_t)b*COUT*HW;

    // epilogue prefetch: Z_old + biases (issued before the staging storm)
    const int h = h0 + ty, w = w0 + tx;
    const size_t si0 = ((size_t)(b*COUT + cg*4))*HW + h*WW + w;
    float zold[4];
    #pragma unroll
    for (int ch = 0; ch < 4; ++ch) zold[ch] = Z[si0 + (size_t)ch*HW];
    float bxr[16], byr[12];
    #pragma unroll
    for (int g = 0; g < 4; ++g)
        #pragma unroll
        for (int ch = 0; ch < 4; ++ch) bxr[g*4+ch] = bx[g*32 + cg*4 + ch];
    #pragma unroll
    for (int g = 0; g < 3; ++g)
        #pragma unroll
        for (int ch = 0; ch < 4; ++ch) byr[g*4+ch] = by[g*32 + cg*4 + ch];

    float ax[16], ay[12];
    #pragma unroll
    for (int i = 0; i < 16; i++) ax[i] = 0.0f;
    #pragma unroll
    for (int i = 0; i < 12; i++) ay[i] = 0.0f;

    StageRegs sr;

    // prologue: stage chunk 0 (X lo) into buf0
    stage_issue(sr, xb, CSX, h0, w0, tid);
    stage_write(tile[0], sr);
    __syncthreads();

    // chunk 0: compute X-lo, stage X-hi into buf1
    stage_issue(sr, xb + (size_t)16*CSX, CSX, h0, w0, tid);
    conv_chunk<4>(tile[0], Wxt + ((size_t)(0*16*8) + cg)*16, ty, tx, ax);
    stage_write(tile[1], sr);
    __syncthreads();

    // chunk 1: compute X-hi, stage Y-lo into buf0
    stage_issue(sr, yb, (size_t)HW, h0, w0, tid);
    conv_chunk<4>(tile[1], Wxt + ((size_t)(1*16*8) + cg)*16, ty, tx, ax);
    stage_write(tile[0], sr);
    __syncthreads();

    // chunk 2: compute Y-lo, stage Y-hi into buf1
    stage_issue(sr, yb + (size_t)16*HW, (size_t)HW, h0, w0, tid);
    conv_chunk<3>(tile[0], Wyt + ((size_t)(0*16*8) + cg)*12, ty, tx, ay);
    stage_write(tile[1], sr);
    __syncthreads();

    // chunk 3: compute Y-hi
    conv_chunk<3>(tile[1], Wyt + ((size_t)(1*16*8) + cg)*12, ty, tx, ay);

    // ---- pointwise: Z update + stash ms2/xy ----
    #pragma unroll
    for (int ch = 0; ch < 4; ++ch) {
        size_t si = si0 + (size_t)ch*HW;
        float g1 = ax[0+ch]  + bxr[0+ch]  + ay[0+ch] + byr[0+ch];
        float g2 = ax[4+ch]  + bxr[4+ch]  + ay[4+ch] + byr[4+ch];
        float zc = ax[8+ch]  + bxr[8+ch]  + ay[8+ch] + byr[8+ch];
        float xy = ax[12+ch] + bxr[12+ch];
        float m1 = fsigmoid(g1);
        float zn = (1.0f - m1) * zold[ch] + m1 * ftanh(zc);
        Z[si]    = zn;
        ms2w[si] = fsigmoid(g2);
        xyw[si]  = xy;
    }
}

// Kernel B: conv(Z_new, Wz) + Y update; writes Y and out[:, :, t]
__global__ __launch_bounds__(512, 4) void lem_update(
    const float* __restrict__ Wzt, const float* __restrict__ bz,
    const float* __restrict__ Z, float* __restrict__ Y,
    const float* __restrict__ ms2w, const float* __restrict__ xyw,
    float* __restrict__ out, int t)
{
    __shared__ __align__(16) float tile[2][TSZ];
    const int tid = threadIdx.x;
    const int tx = tid & 15, ty = (tid >> 4) & 15;
    const int half = __builtin_amdgcn_readfirstlane(tid >> 8);
    const int w0 = blockIdx.x * 16, h0 = blockIdx.y * 16;
    const int b  = blockIdx.z >> 2;
    const int cg = ((blockIdx.z & 3) << 1) | half;

    const float* zb = Z + (size_t)b*COUT*HW;

    // epilogue prefetch
    const int h = h0 + ty, w = w0 + tx;
    const size_t si0 = ((size_t)(b*COUT + cg*4))*HW + h*WW + w;
    float m2r[4], xyr[4], yold[4], bzr[4];
    #pragma unroll
    for (int ch = 0; ch < 4; ++ch) {
        m2r[ch] = ms2w[si0 + (size_t)ch*HW];
        xyr[ch] = xyw[si0 + (size_t)ch*HW];
        yold[ch] = Y[si0 + (size_t)ch*HW];
        bzr[ch] = bz[cg*4 + ch];
    }

    float az[4] = {0.f, 0.f, 0.f, 0.f};
    StageRegs sr;

    // prologue: stage Z-lo into buf0
    stage_issue(sr, zb, (size_t)HW, h0, w0, tid);
    stage_write(tile[0], sr);
    __syncthreads();

    // compute Z-lo, stage Z-hi into buf1
    stage_issue(sr, zb + (size_t)16*HW, (size_t)HW, h0, w0, tid);
    conv_chunk<1>(tile[0], Wzt + ((size_t)(0*16*8) + cg)*4, ty, tx, az);
    stage_write(tile[1], sr);
    __syncthreads();

    // compute Z-hi
    conv_chunk<1>(tile[1], Wzt + ((size_t)(1*16*8) + cg)*4, ty, tx, az);

    #pragma unroll
    for (int ch = 0; ch < 4; ++ch) {
        size_t si = si0 + (size_t)ch*HW;
        float m2 = m2r[ch];
        float yn = (1.0f - m2) * yold[ch] + m2 * ftanh(xyr[ch] + az[ch] + bzr[ch]);
        Y[si] = yn;
        out[((size_t)(b*COUT + cg*4 + ch)*NT + t)*HW + h*WW + w] = yn;
    }
}

extern "C" void kernel_launch(void* const* d_in, const int* in_sizes, int n_in,
                              void* d_out, int out_size, void* d_ws, size_t ws_size,
                              hipStream_t stream)
{
    const float* X  = (const float*)d_in[0];
    const float* Wx = (const float*)d_in[1];
    const float* bx = (const float*)d_in[2];
    const float* Wy = (const float*)d_in[3];
    const float* by = (const float*)d_in[4];
    const float* Wz = (const float*)d_in[5];
    const float* bz = (const float*)d_in[6];
    float* out = (float*)d_out;
    float* ws  = (float*)d_ws;

    const size_t S = (size_t)NB*COUT*HW;
    float* Y   = ws;
    float* Z   = ws + S;
    float* m2w = ws + 2*S;
    float* xyw = ws + 3*S;
    float* Wxt = ws + 4*S;
    float* Wyt = Wxt + 36864;
    float* Wzt = Wyt + 27648;

    hipMemsetAsync(Y, 0, 2*S*sizeof(float), stream);
    wtrans<<<dim3(144), dim3(256), 0, stream>>>(Wx, Wy, Wz, Wxt, Wyt, Wzt);

    dim3 grid(WW/16, HH/16, NB*4);   // 512 blocks of 512 threads
    for (int t = 0; t < NT; t++) {
        lem_gates <<<grid, 512, 0, stream>>>(X, Wxt, bx, Wyt, by, Y, Z, m2w, xyw, t);
        lem_update<<<grid, 512, 0, stream>>>(Wzt, bz, Z, Y, m2w, xyw, out, t);
    }
}